// Round 18
// baseline (147.674 us; speedup 1.0000x reference)
//
#include <hip/hip_runtime.h>
#include <cstdio>

// MHA block for MI355X (gfx950). Round 17:
//  - attn: V-fragments loaded DIRECT from transposed global V (no LDS copy —
//    layout already matches); K keeps LDS staging. LDS ops/block-round 48->24.
//  - gemms: R16 (BK=64, frag-tiled weights global->reg, A via LDS dbuf).
// ws (bf16): Q[S][768] | K[S][768] | Vt[768][S] | AO[S][768] (AO doubles as xb).

using u16 = unsigned short;
typedef __bf16 bf16x8 __attribute__((ext_vector_type(8)));
typedef float f32x4 __attribute__((ext_vector_type(4)));
typedef float f32x16 __attribute__((ext_vector_type(16)));
typedef unsigned int u32x4 __attribute__((ext_vector_type(4)));
typedef u16 u16x4 __attribute__((ext_vector_type(4)));

constexpr int SEQ = 4096;
constexpr int DIM = 768;
constexpr int NH = 12;
constexpr int HD = 64;
constexpr int LDT = 72;   // attn K LDS stride (bf16): 144B rows
constexpr int LDK = 72;   // gemm LDS stride for BK=64 tiles
constexpr int LDM = 68;   // merge stride (f32)
constexpr int NKS = DIM / 32;   // 24 (frag granularity)
constexpr int NS64 = DIM / 64;  // 12 k-steps at BK=64
constexpr float SM_PRE = 0.18033688011112042f;  // (1/8) * log2(e)

__device__ __forceinline__ u16 f2bf(float f) {
  union { float f; unsigned u; } v{f};
  unsigned r = v.u + 0x7fffu + ((v.u >> 16) & 1u);  // RNE
  return (u16)(r >> 16);
}
__device__ __forceinline__ unsigned cvtpk_bf16(float a, float b) {
  unsigned r;
  asm("v_cvt_pk_bf16_f32 %0, %1, %2" : "=v"(r) : "v"(a), "v"(b));
  return r;
}
__device__ __forceinline__ void swap32(unsigned& a, unsigned& b) {
  asm volatile("v_permlane32_swap_b32 %0, %1" : "+v"(a), "+v"(b));
}
__device__ __forceinline__ bf16x8 bc16(const u16* p) {
  return __builtin_bit_cast(bf16x8, *(const u32x4*)p);
}
__device__ __forceinline__ float partner32(float v, int hi) {
  unsigned a = __builtin_bit_cast(unsigned, v), b = a;
  swap32(a, b);
  return __builtin_bit_cast(float, hi ? a : b);
}

// frag layout for a 768x768 weight: [nt16 0..47][ks 0..23][lane 0..63][8 elems]
__device__ __forceinline__ void wfrag_store(const float* __restrict__ w,
                                            u16* __restrict__ wf, int widx) {
  const int lane = widx & 63;
  const int ks = (widx >> 6) % NKS;
  const int nt = widx / (64 * NKS);
  const int n_abs = nt * 16 + (lane & 15);
  const int k0 = ks * 32 + (lane >> 4) * 8;
  const float* s = w + (size_t)n_abs * DIM + k0;
  float4 f0 = *(const float4*)s, f1 = *(const float4*)(s + 4);
  *(u32x4*)(wf + (size_t)widx * 8) =
      u32x4{cvtpk_bf16(f0.x, f0.y), cvtpk_bf16(f0.z, f0.w),
            cvtpk_bf16(f1.x, f1.y), cvtpk_bf16(f1.z, f1.w)};
}

// ---------------- prep: x -> bf16 linear; wq/wk/wv -> frag tiles ----------------
__global__ __launch_bounds__(256) void prep_all(const float* __restrict__ x,
                                                const float* __restrict__ wq,
                                                const float* __restrict__ wk,
                                                const float* __restrict__ wv,
                                                u16* __restrict__ xb,
                                                u16* __restrict__ wqf,
                                                u16* __restrict__ wkf,
                                                u16* __restrict__ wvf) {
  const int blk = blockIdx.x;
  if (blk < 1536) {
    size_t i = ((size_t)blk * 256 + threadIdx.x) * 8;
    float4 f0 = *(const float4*)(x + i);
    float4 f1 = *(const float4*)(x + i + 4);
    *(u32x4*)(xb + i) = u32x4{cvtpk_bf16(f0.x, f0.y), cvtpk_bf16(f0.z, f0.w),
                              cvtpk_bf16(f1.x, f1.y), cvtpk_bf16(f1.z, f1.w)};
  } else {
    const int wi = blk - 1536;
    const int mat = wi / 288;
    const int widx = (wi % 288) * 256 + threadIdx.x;
    const float* src = mat == 0 ? wq : (mat == 1 ? wk : wv);
    u16* dst = mat == 0 ? wqf : (mat == 1 ? wkf : wvf);
    wfrag_store(src, dst, widx);
  }
}

__global__ __launch_bounds__(256) void prep_wfrag(const float* __restrict__ w,
                                                  u16* __restrict__ wf) {
  wfrag_store(w, wf, blockIdx.x * 256 + threadIdx.x);
}

// ---------------- fused QKV GEMM: BK=64, A via LDS dbuf, B from frag tiles ----------------
__global__ __launch_bounds__(256) void qkv_gemm(const u16* __restrict__ xb,
                                                const u16* __restrict__ wqf,
                                                const u16* __restrict__ wkf,
                                                const u16* __restrict__ wvf,
                                                const float* __restrict__ bq,
                                                const float* __restrict__ bk,
                                                const float* __restrict__ bv,
                                                u16* __restrict__ Qb,
                                                u16* __restrict__ Kb,
                                                u16* __restrict__ Vtb) {
  __shared__ alignas(16) u16 As[2][64 * LDK];

  const int tid = threadIdx.x, lane = tid & 63, wave = tid >> 6;
  const int lg = lane >> 4, ln = lane & 15;
  const int bid = blockIdx.x;
  const int swz = (bid & 7) * 96 + (bid >> 3);
  const int mt = swz / 12, nt = swz % 12;
  const int m0 = mt * 64, n0 = nt * 64;
  const int srow = tid >> 2, scol = (tid & 3) * 16;

  f32x4 acc[4][3] = {};

  u32x4 pA0, pA1;
  auto pfA = [&](int kk) {
    const u32x4* s = (const u32x4*)(xb + (size_t)(m0 + srow) * DIM + kk + scol);
    pA0 = s[0]; pA1 = s[1];
  };
  auto stageA = [&](int b) {
    u16* d = &As[b][srow * LDK + scol];
    *(u32x4*)d = pA0;
    *(u32x4*)(d + 8) = pA1;
  };

  const size_t fb = (size_t)(n0 / 16 + wave) * NKS * 512 + (size_t)lane * 8;
  auto ldB = [&](int s, u32x4& q0, u32x4& q1, u32x4& k0, u32x4& k1, u32x4& v0,
                 u32x4& v1) {
    const size_t o0 = fb + (size_t)(2 * s) * 512, o1 = o0 + 512;
    q0 = *(const u32x4*)(wqf + o0); q1 = *(const u32x4*)(wqf + o1);
    k0 = *(const u32x4*)(wkf + o0); k1 = *(const u32x4*)(wkf + o1);
    v0 = *(const u32x4*)(wvf + o0); v1 = *(const u32x4*)(wvf + o1);
  };

  auto body = [&](int s, int cur, u32x4& fQ0, u32x4& fQ1, u32x4& fK0, u32x4& fK1,
                  u32x4& fV0, u32x4& fV1) {
    bf16x8 a0[4], a1[4];
#pragma unroll
    for (int i = 0; i < 4; ++i) {
      a0[i] = bc16(&As[cur][(i * 16 + ln) * LDK + lg * 8]);
      a1[i] = bc16(&As[cur][(i * 16 + ln) * LDK + 32 + lg * 8]);
    }
    if (s + 1 < NS64) {
      stageA(cur ^ 1);
      if (s + 2 < NS64) pfA((s + 2) * 64);
    }
    bf16x8 q0 = __builtin_bit_cast(bf16x8, fQ0), q1 = __builtin_bit_cast(bf16x8, fQ1);
    bf16x8 k0 = __builtin_bit_cast(bf16x8, fK0), k1 = __builtin_bit_cast(bf16x8, fK1);
    bf16x8 v0 = __builtin_bit_cast(bf16x8, fV0), v1 = __builtin_bit_cast(bf16x8, fV1);
#pragma unroll
    for (int i = 0; i < 4; ++i) {
      acc[i][0] = __builtin_amdgcn_mfma_f32_16x16x32_bf16(a0[i], q0, acc[i][0], 0, 0, 0);
      acc[i][1] = __builtin_amdgcn_mfma_f32_16x16x32_bf16(a0[i], k0, acc[i][1], 0, 0, 0);
      acc[i][2] = __builtin_amdgcn_mfma_f32_16x16x32_bf16(a0[i], v0, acc[i][2], 0, 0, 0);
    }
#pragma unroll
    for (int i = 0; i < 4; ++i) {
      acc[i][0] = __builtin_amdgcn_mfma_f32_16x16x32_bf16(a1[i], q1, acc[i][0], 0, 0, 0);
      acc[i][1] = __builtin_amdgcn_mfma_f32_16x16x32_bf16(a1[i], k1, acc[i][1], 0, 0, 0);
      acc[i][2] = __builtin_amdgcn_mfma_f32_16x16x32_bf16(a1[i], v1, acc[i][2], 0, 0, 0);
    }
    __syncthreads();
  };

  pfA(0);
  stageA(0);
  pfA(64);
  u32x4 aq0, aq1, ak0, ak1, av0, av1;
  u32x4 bq0, bq1, bk0, bk1, bv0, bv1;
  ldB(0, aq0, aq1, ak0, ak1, av0, av1);
  ldB(1, bq0, bq1, bk0, bk1, bv0, bv1);
  __syncthreads();

  for (int s = 0; s < NS64; s += 2) {
    body(s, 0, aq0, aq1, ak0, ak1, av0, av1);
    if (s + 2 < NS64) ldB(s + 2, aq0, aq1, ak0, ak1, av0, av1);
    body(s + 1, 1, bq0, bq1, bk0, bk1, bv0, bv1);
    if (s + 3 < NS64) ldB(s + 3, bq0, bq1, bk0, bk1, bv0, bv1);
  }

  const int col = n0 + wave * 16 + ln;
  const float bvq = bq[col], bvk = bk[col], bvv = bv[col];
#pragma unroll
  for (int i = 0; i < 4; ++i) {
    const int rowb = m0 + i * 16 + lg * 4;
#pragma unroll
    for (int r = 0; r < 4; ++r) {
      Qb[(size_t)(rowb + r) * DIM + col] = f2bf((acc[i][0][r] + bvq) * SM_PRE);
      Kb[(size_t)(rowb + r) * DIM + col] = f2bf(acc[i][1][r] + bvk);
    }
    u16x4 pk;
#pragma unroll
    for (int r = 0; r < 4; ++r) pk[r] = f2bf(acc[i][2][r] + bvv);
    *(u16x4*)&Vtb[(size_t)col * SEQ + rowb] = pk;
  }
}

// ---------------- out projection: BK=64, W from frag tiles ----------------
__global__ __launch_bounds__(256) void out_gemm(const u16* __restrict__ Ab,
                                                const u16* __restrict__ wf,
                                                const float* __restrict__ bias,
                                                float* __restrict__ out) {
  __shared__ alignas(16) u16 As[2][64 * LDK];

  const int tid = threadIdx.x, lane = tid & 63, wave = tid >> 6;
  const int lg = lane >> 4, ln = lane & 15;
  const int bid = blockIdx.x;
  const int swz = (bid & 7) * 96 + (bid >> 3);
  const int mt = swz / 12, nt = swz % 12;
  const int m0 = mt * 64, n0 = nt * 64;
  const int srow = tid >> 2, scol = (tid & 3) * 16;

  f32x4 acc[4] = {};

  u32x4 pA0, pA1;
  auto pfA = [&](int kk) {
    const u32x4* s = (const u32x4*)(Ab + (size_t)(m0 + srow) * DIM + kk + scol);
    pA0 = s[0]; pA1 = s[1];
  };
  auto stageA = [&](int b) {
    u16* d = &As[b][srow * LDK + scol];
    *(u32x4*)d = pA0;
    *(u32x4*)(d + 8) = pA1;
  };

  const size_t fb = (size_t)(n0 / 16 + wave) * NKS * 512 + (size_t)lane * 8;
  auto ldW = [&](int s, u32x4& w0, u32x4& w1) {
    const size_t o0 = fb + (size_t)(2 * s) * 512;
    w0 = *(const u32x4*)(wf + o0);
    w1 = *(const u32x4*)(wf + o0 + 512);
  };

  auto body = [&](int s, int cur, u32x4& fW0, u32x4& fW1) {
    bf16x8 a0[4], a1[4];
#pragma unroll
    for (int j = 0; j < 4; ++j) {
      a0[j] = bc16(&As[cur][(j * 16 + ln) * LDK + lg * 8]);
      a1[j] = bc16(&As[cur][(j * 16 + ln) * LDK + 32 + lg * 8]);
    }
    if (s + 1 < NS64) {
      stageA(cur ^ 1);
      if (s + 2 < NS64) pfA((s + 2) * 64);
    }
    bf16x8 w0 = __builtin_bit_cast(bf16x8, fW0), w1 = __builtin_bit_cast(bf16x8, fW1);
#pragma unroll
    for (int j = 0; j < 4; ++j)
      acc[j] = __builtin_amdgcn_mfma_f32_16x16x32_bf16(a0[j], w0, acc[j], 0, 0, 0);
#pragma unroll
    for (int j = 0; j < 4; ++j)
      acc[j] = __builtin_amdgcn_mfma_f32_16x16x32_bf16(a1[j], w1, acc[j], 0, 0, 0);
    __syncthreads();
  };

  pfA(0);
  stageA(0);
  pfA(64);
  u32x4 wA0, wA1, wB0, wB1;
  ldW(0, wA0, wA1);
  ldW(1, wB0, wB1);
  __syncthreads();

  for (int s = 0; s < NS64; s += 2) {
    body(s, 0, wA0, wA1);
    if (s + 2 < NS64) ldW(s + 2, wA0, wA1);
    body(s + 1, 1, wB0, wB1);
    if (s + 3 < NS64) ldW(s + 3, wB0, wB1);
  }

  const int col = n0 + wave * 16 + ln;
  const float bv = bias[col];
#pragma unroll
  for (int j = 0; j < 4; ++j) {
    const int rowb = m0 + j * 16 + lg * 4;
#pragma unroll
    for (int r = 0; r < 4; ++r) out[(size_t)(rowb + r) * DIM + col] = acc[j][r] + bv;
  }
}

// ---------------- flash attention: K via LDS dbuf, V direct from global ----------------
// Grid 768 (64 q-tiles x 12 heads, XCD-swizzled), 4 waves = 2 q-groups x 2
// key-parities. V-frags load straight from Vt (layout already matches); their
// L2 latency hides under QK+softmax. Maxless exp2 softmax.
__global__ __launch_bounds__(256, 3) void attn_kernel(const u16* __restrict__ Q,
                                                      const u16* __restrict__ K,
                                                      const u16* __restrict__ Vt,
                                                      u16* __restrict__ AO) {
  __shared__ alignas(16) u16 Ks[2][64 * LDT];  // [buf][key][d]
  __shared__ float slx[4][32];

  const int tid = threadIdx.x, lane = tid & 63, wave = tid >> 6;
  const int l31 = lane & 31, hi = lane >> 5;
  const int g = wave >> 1, p = wave & 1;
  const int bid = blockIdx.x;
  const int swz = (bid & 7) * 96 + (bid >> 3);  // 768 = 8*96
  const int h = swz >> 6;
  const int q0 = (swz & 63) * 64;
  const int qw = q0 + g * 32;

  bf16x8 qf[4];
#pragma unroll
  for (int c = 0; c < 4; ++c)
    qf[c] = bc16(Q + (size_t)(qw + l31) * DIM + h * HD + c * 16 + hi * 8);

  float l_ = 0.f;
  f32x16 oacc[2] = {};

  const int srow = tid >> 2;
  const int scol = (tid & 3) * 16;
  const u16* Kh = K + (size_t)h * HD;
  const u16* Vh = Vt + (size_t)h * HD * SEQ;
  // per-wave V-frag row bases (row d = nd*32 + l31, key offset p*32 + hi*8)
  const u16* vrow0 = Vh + (size_t)l31 * SEQ + p * 32 + hi * 8;
  const u16* vrow1 = Vh + (size_t)(32 + l31) * SEQ + p * 32 + hi * 8;
  constexpr int NT = SEQ / 64;

  u32x4 kp0, kp1;
  auto pf = [&](int t) {
    const u32x4* s = (const u32x4*)(Kh + (size_t)(t * 64 + srow) * DIM + scol);
    kp0 = s[0]; kp1 = s[1];
  };
  auto stage = [&](int buf) {
    u16* kd = &Ks[buf][srow * LDT + scol];
    *(u32x4*)kd = kp0;
    *(u32x4*)(kd + 8) = kp1;
  };

  pf(0);
  stage(0);
  pf(1);
  __syncthreads();

  auto round = [&](int t, int cur) {
    // K frags from LDS (issued first)
    const int kr = (p * 32 + l31) * LDT + hi * 8;
    bf16x8 kf0 = bc16(&Ks[cur][kr]);
    bf16x8 kf1 = bc16(&Ks[cur][kr + 16]);
    bf16x8 kf2 = bc16(&Ks[cur][kr + 32]);
    bf16x8 kf3 = bc16(&Ks[cur][kr + 48]);
    // V frags direct from global; latency hides under QK + softmax
    bf16x8 vf00 = bc16(vrow0 + t * 64);
    bf16x8 vf01 = bc16(vrow0 + t * 64 + 16);
    bf16x8 vf10 = bc16(vrow1 + t * 64);
    bf16x8 vf11 = bc16(vrow1 + t * 64 + 16);

    if (t + 1 < NT) {
      stage(cur ^ 1);
      pf(t + 2 < NT ? t + 2 : t + 1);
    }

    f32x16 st = {};
    __builtin_amdgcn_s_setprio(1);
    st = __builtin_amdgcn_mfma_f32_32x32x16_bf16(kf0, qf[0], st, 0, 0, 0);
    st = __builtin_amdgcn_mfma_f32_32x32x16_bf16(kf1, qf[1], st, 0, 0, 0);
    st = __builtin_amdgcn_mfma_f32_32x32x16_bf16(kf2, qf[2], st, 0, 0, 0);
    st = __builtin_amdgcn_mfma_f32_32x32x16_bf16(kf3, qf[3], st, 0, 0, 0);
    __builtin_amdgcn_s_setprio(0);

#pragma unroll
    for (int r = 0; r < 16; ++r) st[r] = __builtin_amdgcn_exp2f(st[r]);

    {
      float s0 = (st[0] + st[4]) + (st[8] + st[12]);
      float s1 = (st[1] + st[5]) + (st[9] + st[13]);
      float s2 = (st[2] + st[6]) + (st[10] + st[14]);
      float s3 = (st[3] + st[7]) + (st[11] + st[15]);
      float rs = (s0 + s1) + (s2 + s3);
      l_ += rs + partner32(rs, hi);
    }

    unsigned c0 = cvtpk_bf16(st[0], st[1]), c1 = cvtpk_bf16(st[2], st[3]);
    unsigned c2 = cvtpk_bf16(st[4], st[5]), c3 = cvtpk_bf16(st[6], st[7]);
    unsigned c4 = cvtpk_bf16(st[8], st[9]), c5 = cvtpk_bf16(st[10], st[11]);
    unsigned c6 = cvtpk_bf16(st[12], st[13]), c7 = cvtpk_bf16(st[14], st[15]);
    swap32(c0, c2); swap32(c1, c3); swap32(c4, c6); swap32(c5, c7);
    bf16x8 pa0 = __builtin_bit_cast(bf16x8, u32x4{c0, c1, c2, c3});
    bf16x8 pa1 = __builtin_bit_cast(bf16x8, u32x4{c4, c5, c6, c7});

    __builtin_amdgcn_s_setprio(1);
    oacc[0] = __builtin_amdgcn_mfma_f32_32x32x16_bf16(pa0, vf00, oacc[0], 0, 0, 0);
    oacc[0] = __builtin_amdgcn_mfma_f32_32x32x16_bf16(pa1, vf01, oacc[0], 0, 0, 0);
    oacc[1] = __builtin_amdgcn_mfma_f32_32x32x16_bf16(pa0, vf10, oacc[1], 0, 0, 0);
    oacc[1] = __builtin_amdgcn_mfma_f32_32x32x16_bf16(pa1, vf11, oacc[1], 0, 0, 0);
    __builtin_amdgcn_s_setprio(0);
    __syncthreads();
  };

  for (int t = 0; t < NT; t += 2) {
    round(t, 0);
    round(t + 1, 1);
  }

  if (hi == 0) slx[wave][l31] = l_;
  __syncthreads();

  const float L = slx[g * 2][l31] + slx[g * 2 + 1][l31];
  const float Linv = 1.f / L;
  float Lr[16];
#pragma unroll
  for (int r = 0; r < 16; ++r)
    Lr[r] = __shfl(Linv, (r & 3) + 8 * (r >> 2) + 4 * hi);

  float* Om = (float*)Ks;  // overlay: 64 x LDM f32 = 17408 B (Ks spans 18432)
  if (p == 1) {
#pragma unroll
    for (int nd = 0; nd < 2; ++nd)
#pragma unroll
      for (int r = 0; r < 16; ++r) {
        const int row = (r & 3) + 8 * (r >> 2) + 4 * hi;
        Om[(g * 32 + row) * LDM + nd * 32 + l31] = oacc[nd][r];
      }
  }
  __syncthreads();
  if (p == 0) {
#pragma unroll
    for (int nd = 0; nd < 2; ++nd)
#pragma unroll
      for (int r = 0; r < 16; ++r) {
        const int row = (r & 3) + 8 * (r >> 2) + 4 * hi;
        const float v =
            (oacc[nd][r] + Om[(g * 32 + row) * LDM + nd * 32 + l31]) * Lr[r];
        AO[(size_t)(qw + row) * DIM + h * HD + nd * 32 + l31] = f2bf(v);
      }
  }
}

extern "C" void kernel_launch(void* const* d_in, const int* in_sizes, int n_in,
                              void* d_out, int out_size, void* d_ws, size_t ws_size,
                              hipStream_t stream) {
  const float* x = (const float*)d_in[0];
  const float* wq = (const float*)d_in[1];
  const float* bq = (const float*)d_in[2];
  const float* wk = (const float*)d_in[3];
  const float* bk = (const float*)d_in[4];
  const float* wv = (const float*)d_in[5];
  const float* bv = (const float*)d_in[6];
  const float* ww = (const float*)d_in[7];
  const float* bw = (const float*)d_in[8];

  const size_t mat = (size_t)SEQ * DIM;
  const size_t nw = (size_t)DIM * DIM;
  if (ws_size < 4 * mat * sizeof(u16)) {
    fprintf(stderr, "kernel_launch: ws too small (%zu)\n", ws_size);
    return;
  }
  u16* Qb = (u16*)d_ws;
  u16* Kb = Qb + mat;
  u16* Vtb = Kb + mat;     // [768][4096]
  u16* AOb = Vtb + mat;    // also xb (sequentially dead)
  u16* xb = AOb;
  u16* wqf = (u16*)d_out;  // frag tiles in d_out scratch
  u16* wkf = wqf + nw;
  u16* wvf = wkf + nw;
  u16* wwf = Kb;           // K dead after attn

  prep_all<<<dim3(2400), dim3(256), 0, stream>>>(x, wq, wk, wv, xb, wqf, wkf, wvf);
  qkv_gemm<<<dim3(768), dim3(256), 0, stream>>>(xb, wqf, wkf, wvf, bq, bk, bv, Qb, Kb, Vtb);
  attn_kernel<<<dim3(768), dim3(256), 0, stream>>>(Qb, Kb, Vtb, AOb);
  prep_wfrag<<<dim3(288), dim3(256), 0, stream>>>(ww, wwf);
  out_gemm<<<dim3(768), dim3(256), 0, stream>>>(AOb, wwf, bw, (float*)d_out);
}

// Round 19
// 112.354 us; speedup vs baseline: 1.3144x; 1.3144x over previous
//
#include <hip/hip_runtime.h>
#include <cstdio>

// MHA block for MI355X (gfx950). Round 18 = revert to Round 16 (verified best,
// 112.4 us). R17's V-direct-from-global regressed (scattered 32B requests ->
// L2 request-rate bound, MfmaUtil 31->17.8%): V staging through LDS restored.
//  - gemms: BK=64, frag-tiled weights global->reg, A via LDS dbuf.
//  - attn: K+V LDS dbuf, 1 barrier/round, maxless exp2 softmax, T12 in-reg P.
// ws (bf16): Q[S][768] | K[S][768] | Vt[768][S] | AO[S][768] (AO doubles as xb).

using u16 = unsigned short;
typedef __bf16 bf16x8 __attribute__((ext_vector_type(8)));
typedef float f32x4 __attribute__((ext_vector_type(4)));
typedef float f32x16 __attribute__((ext_vector_type(16)));
typedef unsigned int u32x4 __attribute__((ext_vector_type(4)));
typedef u16 u16x4 __attribute__((ext_vector_type(4)));

constexpr int SEQ = 4096;
constexpr int DIM = 768;
constexpr int NH = 12;
constexpr int HD = 64;
constexpr int LDT = 72;   // attn LDS stride (bf16): 144B rows
constexpr int LDK = 72;   // gemm LDS stride for BK=64 tiles
constexpr int LDM = 68;   // merge stride (f32)
constexpr int NKS = DIM / 32;   // 24 (frag granularity)
constexpr int NS64 = DIM / 64;  // 12 k-steps at BK=64
constexpr float SM_PRE = 0.18033688011112042f;  // (1/8) * log2(e)

__device__ __forceinline__ u16 f2bf(float f) {
  union { float f; unsigned u; } v{f};
  unsigned r = v.u + 0x7fffu + ((v.u >> 16) & 1u);  // RNE
  return (u16)(r >> 16);
}
__device__ __forceinline__ unsigned cvtpk_bf16(float a, float b) {
  unsigned r;
  asm("v_cvt_pk_bf16_f32 %0, %1, %2" : "=v"(r) : "v"(a), "v"(b));
  return r;
}
__device__ __forceinline__ void swap32(unsigned& a, unsigned& b) {
  asm volatile("v_permlane32_swap_b32 %0, %1" : "+v"(a), "+v"(b));
}
__device__ __forceinline__ bf16x8 bc16(const u16* p) {
  return __builtin_bit_cast(bf16x8, *(const u32x4*)p);
}
__device__ __forceinline__ float partner32(float v, int hi) {
  unsigned a = __builtin_bit_cast(unsigned, v), b = a;
  swap32(a, b);
  return __builtin_bit_cast(float, hi ? a : b);
}

// frag layout for a 768x768 weight: [nt16 0..47][ks 0..23][lane 0..63][8 elems]
// lane (lg=lane>>4, ln=lane&15) holds w[nt*16+ln][ks*32 + lg*8 + e].
__device__ __forceinline__ void wfrag_store(const float* __restrict__ w,
                                            u16* __restrict__ wf, int widx) {
  const int lane = widx & 63;
  const int ks = (widx >> 6) % NKS;
  const int nt = widx / (64 * NKS);
  const int n_abs = nt * 16 + (lane & 15);
  const int k0 = ks * 32 + (lane >> 4) * 8;
  const float* s = w + (size_t)n_abs * DIM + k0;
  float4 f0 = *(const float4*)s, f1 = *(const float4*)(s + 4);
  *(u32x4*)(wf + (size_t)widx * 8) =
      u32x4{cvtpk_bf16(f0.x, f0.y), cvtpk_bf16(f0.z, f0.w),
            cvtpk_bf16(f1.x, f1.y), cvtpk_bf16(f1.z, f1.w)};
}

// ---------------- prep: x -> bf16 linear; wq/wk/wv -> frag tiles ----------------
__global__ __launch_bounds__(256) void prep_all(const float* __restrict__ x,
                                                const float* __restrict__ wq,
                                                const float* __restrict__ wk,
                                                const float* __restrict__ wv,
                                                u16* __restrict__ xb,
                                                u16* __restrict__ wqf,
                                                u16* __restrict__ wkf,
                                                u16* __restrict__ wvf) {
  const int blk = blockIdx.x;
  if (blk < 1536) {  // x: 3.145M elems, 8 per thread
    size_t i = ((size_t)blk * 256 + threadIdx.x) * 8;
    float4 f0 = *(const float4*)(x + i);
    float4 f1 = *(const float4*)(x + i + 4);
    *(u32x4*)(xb + i) = u32x4{cvtpk_bf16(f0.x, f0.y), cvtpk_bf16(f0.z, f0.w),
                              cvtpk_bf16(f1.x, f1.y), cvtpk_bf16(f1.z, f1.w)};
  } else {  // 864 blocks: 288 per weight matrix
    const int wi = blk - 1536;
    const int mat = wi / 288;
    const int widx = (wi % 288) * 256 + threadIdx.x;
    const float* src = mat == 0 ? wq : (mat == 1 ? wk : wv);
    u16* dst = mat == 0 ? wqf : (mat == 1 ? wkf : wvf);
    wfrag_store(src, dst, widx);
  }
}

// ww -> frag tiles (runs after attn; dst overlays dead K buffer)
__global__ __launch_bounds__(256) void prep_wfrag(const float* __restrict__ w,
                                                  u16* __restrict__ wf) {
  wfrag_store(w, wf, blockIdx.x * 256 + threadIdx.x);
}

// ---------------- fused QKV GEMM: BK=64, A via LDS dbuf, B from frag tiles ----------------
__global__ __launch_bounds__(256) void qkv_gemm(const u16* __restrict__ xb,
                                                const u16* __restrict__ wqf,
                                                const u16* __restrict__ wkf,
                                                const u16* __restrict__ wvf,
                                                const float* __restrict__ bq,
                                                const float* __restrict__ bk,
                                                const float* __restrict__ bv,
                                                u16* __restrict__ Qb,
                                                u16* __restrict__ Kb,
                                                u16* __restrict__ Vtb) {
  __shared__ alignas(16) u16 As[2][64 * LDK];

  const int tid = threadIdx.x, lane = tid & 63, wave = tid >> 6;
  const int lg = lane >> 4, ln = lane & 15;
  const int bid = blockIdx.x;
  const int swz = (bid & 7) * 96 + (bid >> 3);
  const int mt = swz / 12, nt = swz % 12;
  const int m0 = mt * 64, n0 = nt * 64;
  const int srow = tid >> 2, scol = (tid & 3) * 16;

  f32x4 acc[4][3] = {};  // [m-tile][output]

  u32x4 pA0, pA1;
  auto pfA = [&](int kk) {
    const u32x4* s = (const u32x4*)(xb + (size_t)(m0 + srow) * DIM + kk + scol);
    pA0 = s[0]; pA1 = s[1];
  };
  auto stageA = [&](int b) {
    u16* d = &As[b][srow * LDK + scol];
    *(u32x4*)d = pA0;
    *(u32x4*)(d + 8) = pA1;
  };

  // B frag base: nt16 = n0/16 + wave; 512 elems per (nt,ks); step s uses ks=2s,2s+1
  const size_t fb = (size_t)(n0 / 16 + wave) * NKS * 512 + (size_t)lane * 8;
  auto ldB = [&](int s, u32x4& q0, u32x4& q1, u32x4& k0, u32x4& k1, u32x4& v0,
                 u32x4& v1) {
    const size_t o0 = fb + (size_t)(2 * s) * 512, o1 = o0 + 512;
    q0 = *(const u32x4*)(wqf + o0); q1 = *(const u32x4*)(wqf + o1);
    k0 = *(const u32x4*)(wkf + o0); k1 = *(const u32x4*)(wkf + o1);
    v0 = *(const u32x4*)(wvf + o0); v1 = *(const u32x4*)(wvf + o1);
  };

  auto body = [&](int s, int cur, u32x4& fQ0, u32x4& fQ1, u32x4& fK0, u32x4& fK1,
                  u32x4& fV0, u32x4& fV1) {
    bf16x8 a0[4], a1[4];
#pragma unroll
    for (int i = 0; i < 4; ++i) {
      a0[i] = bc16(&As[cur][(i * 16 + ln) * LDK + lg * 8]);
      a1[i] = bc16(&As[cur][(i * 16 + ln) * LDK + 32 + lg * 8]);
    }
    if (s + 1 < NS64) {
      stageA(cur ^ 1);
      if (s + 2 < NS64) pfA((s + 2) * 64);
    }
    bf16x8 q0 = __builtin_bit_cast(bf16x8, fQ0), q1 = __builtin_bit_cast(bf16x8, fQ1);
    bf16x8 k0 = __builtin_bit_cast(bf16x8, fK0), k1 = __builtin_bit_cast(bf16x8, fK1);
    bf16x8 v0 = __builtin_bit_cast(bf16x8, fV0), v1 = __builtin_bit_cast(bf16x8, fV1);
#pragma unroll
    for (int i = 0; i < 4; ++i) {
      acc[i][0] = __builtin_amdgcn_mfma_f32_16x16x32_bf16(a0[i], q0, acc[i][0], 0, 0, 0);
      acc[i][1] = __builtin_amdgcn_mfma_f32_16x16x32_bf16(a0[i], k0, acc[i][1], 0, 0, 0);
      acc[i][2] = __builtin_amdgcn_mfma_f32_16x16x32_bf16(a0[i], v0, acc[i][2], 0, 0, 0);
    }
#pragma unroll
    for (int i = 0; i < 4; ++i) {
      acc[i][0] = __builtin_amdgcn_mfma_f32_16x16x32_bf16(a1[i], q1, acc[i][0], 0, 0, 0);
      acc[i][1] = __builtin_amdgcn_mfma_f32_16x16x32_bf16(a1[i], k1, acc[i][1], 0, 0, 0);
      acc[i][2] = __builtin_amdgcn_mfma_f32_16x16x32_bf16(a1[i], v1, acc[i][2], 0, 0, 0);
    }
    __syncthreads();
  };

  pfA(0);
  stageA(0);
  pfA(64);
  u32x4 aq0, aq1, ak0, ak1, av0, av1;
  u32x4 bq0, bq1, bk0, bk1, bv0, bv1;
  ldB(0, aq0, aq1, ak0, ak1, av0, av1);
  ldB(1, bq0, bq1, bk0, bk1, bv0, bv1);
  __syncthreads();

  for (int s = 0; s < NS64; s += 2) {
    body(s, 0, aq0, aq1, ak0, ak1, av0, av1);
    if (s + 2 < NS64) ldB(s + 2, aq0, aq1, ak0, ak1, av0, av1);
    body(s + 1, 1, bq0, bq1, bk0, bk1, bv0, bv1);
    if (s + 3 < NS64) ldB(s + 3, bq0, bq1, bk0, bk1, bv0, bv1);
  }

  const int col = n0 + wave * 16 + ln;
  const float bvq = bq[col], bvk = bk[col], bvv = bv[col];
#pragma unroll
  for (int i = 0; i < 4; ++i) {
    const int rowb = m0 + i * 16 + lg * 4;
#pragma unroll
    for (int r = 0; r < 4; ++r) {
      Qb[(size_t)(rowb + r) * DIM + col] = f2bf((acc[i][0][r] + bvq) * SM_PRE);
      Kb[(size_t)(rowb + r) * DIM + col] = f2bf(acc[i][1][r] + bvk);
    }
    u16x4 pk;
#pragma unroll
    for (int r = 0; r < 4; ++r) pk[r] = f2bf(acc[i][2][r] + bvv);
    *(u16x4*)&Vtb[(size_t)col * SEQ + rowb] = pk;
  }
}

// ---------------- out projection: BK=64, W from frag tiles ----------------
__global__ __launch_bounds__(256) void out_gemm(const u16* __restrict__ Ab,
                                                const u16* __restrict__ wf,
                                                const float* __restrict__ bias,
                                                float* __restrict__ out) {
  __shared__ alignas(16) u16 As[2][64 * LDK];

  const int tid = threadIdx.x, lane = tid & 63, wave = tid >> 6;
  const int lg = lane >> 4, ln = lane & 15;
  const int bid = blockIdx.x;
  const int swz = (bid & 7) * 96 + (bid >> 3);
  const int mt = swz / 12, nt = swz % 12;
  const int m0 = mt * 64, n0 = nt * 64;
  const int srow = tid >> 2, scol = (tid & 3) * 16;

  f32x4 acc[4] = {};

  u32x4 pA0, pA1;
  auto pfA = [&](int kk) {
    const u32x4* s = (const u32x4*)(Ab + (size_t)(m0 + srow) * DIM + kk + scol);
    pA0 = s[0]; pA1 = s[1];
  };
  auto stageA = [&](int b) {
    u16* d = &As[b][srow * LDK + scol];
    *(u32x4*)d = pA0;
    *(u32x4*)(d + 8) = pA1;
  };

  const size_t fb = (size_t)(n0 / 16 + wave) * NKS * 512 + (size_t)lane * 8;
  auto ldW = [&](int s, u32x4& w0, u32x4& w1) {
    const size_t o0 = fb + (size_t)(2 * s) * 512;
    w0 = *(const u32x4*)(wf + o0);
    w1 = *(const u32x4*)(wf + o0 + 512);
  };

  auto body = [&](int s, int cur, u32x4& fW0, u32x4& fW1) {
    bf16x8 a0[4], a1[4];
#pragma unroll
    for (int j = 0; j < 4; ++j) {
      a0[j] = bc16(&As[cur][(j * 16 + ln) * LDK + lg * 8]);
      a1[j] = bc16(&As[cur][(j * 16 + ln) * LDK + 32 + lg * 8]);
    }
    if (s + 1 < NS64) {
      stageA(cur ^ 1);
      if (s + 2 < NS64) pfA((s + 2) * 64);
    }
    bf16x8 w0 = __builtin_bit_cast(bf16x8, fW0), w1 = __builtin_bit_cast(bf16x8, fW1);
#pragma unroll
    for (int j = 0; j < 4; ++j)
      acc[j] = __builtin_amdgcn_mfma_f32_16x16x32_bf16(a0[j], w0, acc[j], 0, 0, 0);
#pragma unroll
    for (int j = 0; j < 4; ++j)
      acc[j] = __builtin_amdgcn_mfma_f32_16x16x32_bf16(a1[j], w1, acc[j], 0, 0, 0);
    __syncthreads();
  };

  pfA(0);
  stageA(0);
  pfA(64);
  u32x4 wA0, wA1, wB0, wB1;
  ldW(0, wA0, wA1);
  ldW(1, wB0, wB1);
  __syncthreads();

  for (int s = 0; s < NS64; s += 2) {
    body(s, 0, wA0, wA1);
    if (s + 2 < NS64) ldW(s + 2, wA0, wA1);
    body(s + 1, 1, wB0, wB1);
    if (s + 3 < NS64) ldW(s + 3, wB0, wB1);
  }

  const int col = n0 + wave * 16 + ln;
  const float bv = bias[col];
#pragma unroll
  for (int j = 0; j < 4; ++j) {
    const int rowb = m0 + j * 16 + lg * 4;
#pragma unroll
    for (int r = 0; r < 4; ++r) out[(size_t)(rowb + r) * DIM + col] = acc[j][r] + bv;
  }
}

// ---------------- flash attention: K+V LDS dbuf, maxless exp2 softmax ----------------
// Grid 768 (64 q-tiles x 12 heads, XCD-swizzled), 4 waves = 2 q-groups x 2
// key-parities. Wave (g,p): q rows qt*64+g*32.., keys t*64+p*32.
__global__ __launch_bounds__(256, 3) void attn_kernel(const u16* __restrict__ Q,
                                                      const u16* __restrict__ K,
                                                      const u16* __restrict__ Vt,
                                                      u16* __restrict__ AO) {
  __shared__ alignas(16) u16 Ks[2][64 * LDT];  // [buf][key][d]
  __shared__ alignas(16) u16 Vs[2][64 * LDT];  // [buf][d][key]
  __shared__ float slx[4][32];

  const int tid = threadIdx.x, lane = tid & 63, wave = tid >> 6;
  const int l31 = lane & 31, hi = lane >> 5;
  const int g = wave >> 1, p = wave & 1;
  const int bid = blockIdx.x;
  const int swz = (bid & 7) * 96 + (bid >> 3);  // 768 = 8*96
  const int h = swz >> 6;
  const int q0 = (swz & 63) * 64;
  const int qw = q0 + g * 32;

  bf16x8 qf[4];
#pragma unroll
  for (int c = 0; c < 4; ++c)
    qf[c] = bc16(Q + (size_t)(qw + l31) * DIM + h * HD + c * 16 + hi * 8);

  float l_ = 0.f;
  f32x16 oacc[2] = {};

  const int srow = tid >> 2;
  const int scol = (tid & 3) * 16;
  const u16* Kh = K + (size_t)h * HD;
  const u16* Vh = Vt + (size_t)h * HD * SEQ;
  constexpr int NT = SEQ / 64;

  u32x4 kp0, kp1, vp0, vp1;
  auto pf = [&](int t) {
    const u32x4* s = (const u32x4*)(Kh + (size_t)(t * 64 + srow) * DIM + scol);
    kp0 = s[0]; kp1 = s[1];
    const u32x4* v = (const u32x4*)(Vh + (size_t)srow * SEQ + t * 64 + scol);
    vp0 = v[0]; vp1 = v[1];
  };
  auto stage = [&](int buf) {
    u16* kd = &Ks[buf][srow * LDT + scol];
    *(u32x4*)kd = kp0; *(u32x4*)(kd + 8) = kp1;
    u16* vd = &Vs[buf][srow * LDT + scol];
    *(u32x4*)vd = vp0; *(u32x4*)(vd + 8) = vp1;
  };

  pf(0);
  stage(0);
  pf(1);
  __syncthreads();

  auto round = [&](int t, int cur) {
    const int kr = (p * 32 + l31) * LDT + hi * 8;
    bf16x8 kf0 = bc16(&Ks[cur][kr]);
    bf16x8 kf1 = bc16(&Ks[cur][kr + 16]);
    bf16x8 kf2 = bc16(&Ks[cur][kr + 32]);
    bf16x8 kf3 = bc16(&Ks[cur][kr + 48]);
    const int vr0 = l31 * LDT + p * 32 + hi * 8;
    const int vr1 = (32 + l31) * LDT + p * 32 + hi * 8;
    bf16x8 vf00 = bc16(&Vs[cur][vr0]);
    bf16x8 vf01 = bc16(&Vs[cur][vr0 + 16]);
    bf16x8 vf10 = bc16(&Vs[cur][vr1]);
    bf16x8 vf11 = bc16(&Vs[cur][vr1 + 16]);

    if (t + 1 < NT) {
      stage(cur ^ 1);
      pf(t + 2 < NT ? t + 2 : t + 1);
    }

    f32x16 st = {};
    __builtin_amdgcn_s_setprio(1);
    st = __builtin_amdgcn_mfma_f32_32x32x16_bf16(kf0, qf[0], st, 0, 0, 0);
    st = __builtin_amdgcn_mfma_f32_32x32x16_bf16(kf1, qf[1], st, 0, 0, 0);
    st = __builtin_amdgcn_mfma_f32_32x32x16_bf16(kf2, qf[2], st, 0, 0, 0);
    st = __builtin_amdgcn_mfma_f32_32x32x16_bf16(kf3, qf[3], st, 0, 0, 0);
    __builtin_amdgcn_s_setprio(0);

#pragma unroll
    for (int r = 0; r < 16; ++r) st[r] = __builtin_amdgcn_exp2f(st[r]);

    {
      float s0 = (st[0] + st[4]) + (st[8] + st[12]);
      float s1 = (st[1] + st[5]) + (st[9] + st[13]);
      float s2 = (st[2] + st[6]) + (st[10] + st[14]);
      float s3 = (st[3] + st[7]) + (st[11] + st[15]);
      float rs = (s0 + s1) + (s2 + s3);
      l_ += rs + partner32(rs, hi);
    }

    unsigned c0 = cvtpk_bf16(st[0], st[1]), c1 = cvtpk_bf16(st[2], st[3]);
    unsigned c2 = cvtpk_bf16(st[4], st[5]), c3 = cvtpk_bf16(st[6], st[7]);
    unsigned c4 = cvtpk_bf16(st[8], st[9]), c5 = cvtpk_bf16(st[10], st[11]);
    unsigned c6 = cvtpk_bf16(st[12], st[13]), c7 = cvtpk_bf16(st[14], st[15]);
    swap32(c0, c2); swap32(c1, c3); swap32(c4, c6); swap32(c5, c7);
    bf16x8 pa0 = __builtin_bit_cast(bf16x8, u32x4{c0, c1, c2, c3});
    bf16x8 pa1 = __builtin_bit_cast(bf16x8, u32x4{c4, c5, c6, c7});

    __builtin_amdgcn_s_setprio(1);
    oacc[0] = __builtin_amdgcn_mfma_f32_32x32x16_bf16(pa0, vf00, oacc[0], 0, 0, 0);
    oacc[0] = __builtin_amdgcn_mfma_f32_32x32x16_bf16(pa1, vf01, oacc[0], 0, 0, 0);
    oacc[1] = __builtin_amdgcn_mfma_f32_32x32x16_bf16(pa0, vf10, oacc[1], 0, 0, 0);
    oacc[1] = __builtin_amdgcn_mfma_f32_32x32x16_bf16(pa1, vf11, oacc[1], 0, 0, 0);
    __builtin_amdgcn_s_setprio(0);
    __syncthreads();
  };

  for (int t = 0; t < NT; t += 2) {
    round(t, 0);
    round(t + 1, 1);
  }

  if (hi == 0) slx[wave][l31] = l_;
  __syncthreads();

  const float L = slx[g * 2][l31] + slx[g * 2 + 1][l31];
  const float Linv = 1.f / L;
  float Lr[16];
#pragma unroll
  for (int r = 0; r < 16; ++r)
    Lr[r] = __shfl(Linv, (r & 3) + 8 * (r >> 2) + 4 * hi);

  float* Om = (float*)Ks;  // overlay: 64 x LDM f32 = 17408 B (Ks spans 18432)
  if (p == 1) {
#pragma unroll
    for (int nd = 0; nd < 2; ++nd)
#pragma unroll
      for (int r = 0; r < 16; ++r) {
        const int row = (r & 3) + 8 * (r >> 2) + 4 * hi;
        Om[(g * 32 + row) * LDM + nd * 32 + l31] = oacc[nd][r];
      }
  }
  __syncthreads();
  if (p == 0) {
#pragma unroll
    for (int nd = 0; nd < 2; ++nd)
#pragma unroll
      for (int r = 0; r < 16; ++r) {
        const int row = (r & 3) + 8 * (r >> 2) + 4 * hi;
        const float v =
            (oacc[nd][r] + Om[(g * 32 + row) * LDM + nd * 32 + l31]) * Lr[r];
        AO[(size_t)(qw + row) * DIM + h * HD + nd * 32 + l31] = f2bf(v);
      }
  }
}

extern "C" void kernel_launch(void* const* d_in, const int* in_sizes, int n_in,
                              void* d_out, int out_size, void* d_ws, size_t ws_size,
                              hipStream_t stream) {
  const float* x = (const float*)d_in[0];
  const float* wq = (const float*)d_in[1];
  const float* bq = (const float*)d_in[2];
  const float* wk = (const float*)d_in[3];
  const float* bk = (const float*)d_in[4];
  const float* wv = (const float*)d_in[5];
  const float* bv = (const float*)d_in[6];
  const float* ww = (const float*)d_in[7];
  const float* bw = (const float*)d_in[8];

  const size_t mat = (size_t)SEQ * DIM;
  const size_t nw = (size_t)DIM * DIM;  // 589,824
  if (ws_size < 4 * mat * sizeof(u16)) {
    fprintf(stderr, "kernel_launch: ws too small (%zu)\n", ws_size);
    return;
  }
  u16* Qb = (u16*)d_ws;
  u16* Kb = Qb + mat;
  u16* Vtb = Kb + mat;     // [768][4096]
  u16* AOb = Vtb + mat;    // also xb (sequentially dead)
  u16* xb = AOb;
  u16* wqf = (u16*)d_out;  // frag tiles in d_out scratch (consumed pre-out_gemm)
  u16* wkf = wqf + nw;
  u16* wvf = wkf + nw;
  u16* wwf = Kb;           // K dead after attn

  prep_all<<<dim3(2400), dim3(256), 0, stream>>>(x, wq, wk, wv, xb, wqf, wkf, wvf);
  qkv_gemm<<<dim3(768), dim3(256), 0, stream>>>(xb, wqf, wkf, wvf, bq, bk, bv, Qb, Kb, Vtb);
  attn_kernel<<<dim3(768), dim3(256), 0, stream>>>(Qb, Kb, Vtb, AOb);
  prep_wfrag<<<dim3(288), dim3(256), 0, stream>>>(ww, wwf);
  out_gemm<<<dim3(768), dim3(256), 0, stream>>>(AOb, wwf, bw, (float*)d_out);
}

// Round 20
// 112.002 us; speedup vs baseline: 1.3185x; 1.0031x over previous
//
#include <hip/hip_runtime.h>
#include <cstdio>

// MHA block for MI355X (gfx950). Round 19 = champion (R16/R18, 112.35 us) with
// one provably-identical micro-fix: the cross-half partner32 exchange of the
// softmax row-sum is deferred out of the 64-round loop (sum is linear in the
// fixed lane pairing), removing ~3 VALU ops per round.
//  - gemms: BK=64, frag-tiled weights global->reg, A via LDS dbuf.
//  - attn: K+V LDS dbuf, 1 barrier/round, maxless exp2 softmax, T12 in-reg P.
// ws (bf16): Q[S][768] | K[S][768] | Vt[768][S] | AO[S][768] (AO doubles as xb).

using u16 = unsigned short;
typedef __bf16 bf16x8 __attribute__((ext_vector_type(8)));
typedef float f32x4 __attribute__((ext_vector_type(4)));
typedef float f32x16 __attribute__((ext_vector_type(16)));
typedef unsigned int u32x4 __attribute__((ext_vector_type(4)));
typedef u16 u16x4 __attribute__((ext_vector_type(4)));

constexpr int SEQ = 4096;
constexpr int DIM = 768;
constexpr int NH = 12;
constexpr int HD = 64;
constexpr int LDT = 72;   // attn LDS stride (bf16): 144B rows
constexpr int LDK = 72;   // gemm LDS stride for BK=64 tiles
constexpr int LDM = 68;   // merge stride (f32)
constexpr int NKS = DIM / 32;   // 24 (frag granularity)
constexpr int NS64 = DIM / 64;  // 12 k-steps at BK=64
constexpr float SM_PRE = 0.18033688011112042f;  // (1/8) * log2(e)

__device__ __forceinline__ u16 f2bf(float f) {
  union { float f; unsigned u; } v{f};
  unsigned r = v.u + 0x7fffu + ((v.u >> 16) & 1u);  // RNE
  return (u16)(r >> 16);
}
__device__ __forceinline__ unsigned cvtpk_bf16(float a, float b) {
  unsigned r;
  asm("v_cvt_pk_bf16_f32 %0, %1, %2" : "=v"(r) : "v"(a), "v"(b));
  return r;
}
__device__ __forceinline__ void swap32(unsigned& a, unsigned& b) {
  asm volatile("v_permlane32_swap_b32 %0, %1" : "+v"(a), "+v"(b));
}
__device__ __forceinline__ bf16x8 bc16(const u16* p) {
  return __builtin_bit_cast(bf16x8, *(const u32x4*)p);
}
__device__ __forceinline__ float partner32(float v, int hi) {
  unsigned a = __builtin_bit_cast(unsigned, v), b = a;
  swap32(a, b);
  return __builtin_bit_cast(float, hi ? a : b);
}

// frag layout for a 768x768 weight: [nt16 0..47][ks 0..23][lane 0..63][8 elems]
// lane (lg=lane>>4, ln=lane&15) holds w[nt*16+ln][ks*32 + lg*8 + e].
__device__ __forceinline__ void wfrag_store(const float* __restrict__ w,
                                            u16* __restrict__ wf, int widx) {
  const int lane = widx & 63;
  const int ks = (widx >> 6) % NKS;
  const int nt = widx / (64 * NKS);
  const int n_abs = nt * 16 + (lane & 15);
  const int k0 = ks * 32 + (lane >> 4) * 8;
  const float* s = w + (size_t)n_abs * DIM + k0;
  float4 f0 = *(const float4*)s, f1 = *(const float4*)(s + 4);
  *(u32x4*)(wf + (size_t)widx * 8) =
      u32x4{cvtpk_bf16(f0.x, f0.y), cvtpk_bf16(f0.z, f0.w),
            cvtpk_bf16(f1.x, f1.y), cvtpk_bf16(f1.z, f1.w)};
}

// ---------------- prep: x -> bf16 linear; wq/wk/wv -> frag tiles ----------------
__global__ __launch_bounds__(256) void prep_all(const float* __restrict__ x,
                                                const float* __restrict__ wq,
                                                const float* __restrict__ wk,
                                                const float* __restrict__ wv,
                                                u16* __restrict__ xb,
                                                u16* __restrict__ wqf,
                                                u16* __restrict__ wkf,
                                                u16* __restrict__ wvf) {
  const int blk = blockIdx.x;
  if (blk < 1536) {  // x: 3.145M elems, 8 per thread
    size_t i = ((size_t)blk * 256 + threadIdx.x) * 8;
    float4 f0 = *(const float4*)(x + i);
    float4 f1 = *(const float4*)(x + i + 4);
    *(u32x4*)(xb + i) = u32x4{cvtpk_bf16(f0.x, f0.y), cvtpk_bf16(f0.z, f0.w),
                              cvtpk_bf16(f1.x, f1.y), cvtpk_bf16(f1.z, f1.w)};
  } else {  // 864 blocks: 288 per weight matrix
    const int wi = blk - 1536;
    const int mat = wi / 288;
    const int widx = (wi % 288) * 256 + threadIdx.x;
    const float* src = mat == 0 ? wq : (mat == 1 ? wk : wv);
    u16* dst = mat == 0 ? wqf : (mat == 1 ? wkf : wvf);
    wfrag_store(src, dst, widx);
  }
}

// ww -> frag tiles (runs after attn; dst overlays dead K buffer)
__global__ __launch_bounds__(256) void prep_wfrag(const float* __restrict__ w,
                                                  u16* __restrict__ wf) {
  wfrag_store(w, wf, blockIdx.x * 256 + threadIdx.x);
}

// ---------------- fused QKV GEMM: BK=64, A via LDS dbuf, B from frag tiles ----------------
__global__ __launch_bounds__(256) void qkv_gemm(const u16* __restrict__ xb,
                                                const u16* __restrict__ wqf,
                                                const u16* __restrict__ wkf,
                                                const u16* __restrict__ wvf,
                                                const float* __restrict__ bq,
                                                const float* __restrict__ bk,
                                                const float* __restrict__ bv,
                                                u16* __restrict__ Qb,
                                                u16* __restrict__ Kb,
                                                u16* __restrict__ Vtb) {
  __shared__ alignas(16) u16 As[2][64 * LDK];

  const int tid = threadIdx.x, lane = tid & 63, wave = tid >> 6;
  const int lg = lane >> 4, ln = lane & 15;
  const int bid = blockIdx.x;
  const int swz = (bid & 7) * 96 + (bid >> 3);
  const int mt = swz / 12, nt = swz % 12;
  const int m0 = mt * 64, n0 = nt * 64;
  const int srow = tid >> 2, scol = (tid & 3) * 16;

  f32x4 acc[4][3] = {};  // [m-tile][output]

  u32x4 pA0, pA1;
  auto pfA = [&](int kk) {
    const u32x4* s = (const u32x4*)(xb + (size_t)(m0 + srow) * DIM + kk + scol);
    pA0 = s[0]; pA1 = s[1];
  };
  auto stageA = [&](int b) {
    u16* d = &As[b][srow * LDK + scol];
    *(u32x4*)d = pA0;
    *(u32x4*)(d + 8) = pA1;
  };

  // B frag base: nt16 = n0/16 + wave; 512 elems per (nt,ks); step s uses ks=2s,2s+1
  const size_t fb = (size_t)(n0 / 16 + wave) * NKS * 512 + (size_t)lane * 8;
  auto ldB = [&](int s, u32x4& q0, u32x4& q1, u32x4& k0, u32x4& k1, u32x4& v0,
                 u32x4& v1) {
    const size_t o0 = fb + (size_t)(2 * s) * 512, o1 = o0 + 512;
    q0 = *(const u32x4*)(wqf + o0); q1 = *(const u32x4*)(wqf + o1);
    k0 = *(const u32x4*)(wkf + o0); k1 = *(const u32x4*)(wkf + o1);
    v0 = *(const u32x4*)(wvf + o0); v1 = *(const u32x4*)(wvf + o1);
  };

  auto body = [&](int s, int cur, u32x4& fQ0, u32x4& fQ1, u32x4& fK0, u32x4& fK1,
                  u32x4& fV0, u32x4& fV1) {
    bf16x8 a0[4], a1[4];
#pragma unroll
    for (int i = 0; i < 4; ++i) {
      a0[i] = bc16(&As[cur][(i * 16 + ln) * LDK + lg * 8]);
      a1[i] = bc16(&As[cur][(i * 16 + ln) * LDK + 32 + lg * 8]);
    }
    if (s + 1 < NS64) {
      stageA(cur ^ 1);
      if (s + 2 < NS64) pfA((s + 2) * 64);
    }
    bf16x8 q0 = __builtin_bit_cast(bf16x8, fQ0), q1 = __builtin_bit_cast(bf16x8, fQ1);
    bf16x8 k0 = __builtin_bit_cast(bf16x8, fK0), k1 = __builtin_bit_cast(bf16x8, fK1);
    bf16x8 v0 = __builtin_bit_cast(bf16x8, fV0), v1 = __builtin_bit_cast(bf16x8, fV1);
#pragma unroll
    for (int i = 0; i < 4; ++i) {
      acc[i][0] = __builtin_amdgcn_mfma_f32_16x16x32_bf16(a0[i], q0, acc[i][0], 0, 0, 0);
      acc[i][1] = __builtin_amdgcn_mfma_f32_16x16x32_bf16(a0[i], k0, acc[i][1], 0, 0, 0);
      acc[i][2] = __builtin_amdgcn_mfma_f32_16x16x32_bf16(a0[i], v0, acc[i][2], 0, 0, 0);
    }
#pragma unroll
    for (int i = 0; i < 4; ++i) {
      acc[i][0] = __builtin_amdgcn_mfma_f32_16x16x32_bf16(a1[i], q1, acc[i][0], 0, 0, 0);
      acc[i][1] = __builtin_amdgcn_mfma_f32_16x16x32_bf16(a1[i], k1, acc[i][1], 0, 0, 0);
      acc[i][2] = __builtin_amdgcn_mfma_f32_16x16x32_bf16(a1[i], v1, acc[i][2], 0, 0, 0);
    }
    __syncthreads();
  };

  pfA(0);
  stageA(0);
  pfA(64);
  u32x4 aq0, aq1, ak0, ak1, av0, av1;
  u32x4 bq0, bq1, bk0, bk1, bv0, bv1;
  ldB(0, aq0, aq1, ak0, ak1, av0, av1);
  ldB(1, bq0, bq1, bk0, bk1, bv0, bv1);
  __syncthreads();

  for (int s = 0; s < NS64; s += 2) {
    body(s, 0, aq0, aq1, ak0, ak1, av0, av1);
    if (s + 2 < NS64) ldB(s + 2, aq0, aq1, ak0, ak1, av0, av1);
    body(s + 1, 1, bq0, bq1, bk0, bk1, bv0, bv1);
    if (s + 3 < NS64) ldB(s + 3, bq0, bq1, bk0, bk1, bv0, bv1);
  }

  const int col = n0 + wave * 16 + ln;
  const float bvq = bq[col], bvk = bk[col], bvv = bv[col];
#pragma unroll
  for (int i = 0; i < 4; ++i) {
    const int rowb = m0 + i * 16 + lg * 4;
#pragma unroll
    for (int r = 0; r < 4; ++r) {
      Qb[(size_t)(rowb + r) * DIM + col] = f2bf((acc[i][0][r] + bvq) * SM_PRE);
      Kb[(size_t)(rowb + r) * DIM + col] = f2bf(acc[i][1][r] + bvk);
    }
    u16x4 pk;
#pragma unroll
    for (int r = 0; r < 4; ++r) pk[r] = f2bf(acc[i][2][r] + bvv);
    *(u16x4*)&Vtb[(size_t)col * SEQ + rowb] = pk;
  }
}

// ---------------- out projection: BK=64, W from frag tiles ----------------
__global__ __launch_bounds__(256) void out_gemm(const u16* __restrict__ Ab,
                                                const u16* __restrict__ wf,
                                                const float* __restrict__ bias,
                                                float* __restrict__ out) {
  __shared__ alignas(16) u16 As[2][64 * LDK];

  const int tid = threadIdx.x, lane = tid & 63, wave = tid >> 6;
  const int lg = lane >> 4, ln = lane & 15;
  const int bid = blockIdx.x;
  const int swz = (bid & 7) * 96 + (bid >> 3);
  const int mt = swz / 12, nt = swz % 12;
  const int m0 = mt * 64, n0 = nt * 64;
  const int srow = tid >> 2, scol = (tid & 3) * 16;

  f32x4 acc[4] = {};

  u32x4 pA0, pA1;
  auto pfA = [&](int kk) {
    const u32x4* s = (const u32x4*)(Ab + (size_t)(m0 + srow) * DIM + kk + scol);
    pA0 = s[0]; pA1 = s[1];
  };
  auto stageA = [&](int b) {
    u16* d = &As[b][srow * LDK + scol];
    *(u32x4*)d = pA0;
    *(u32x4*)(d + 8) = pA1;
  };

  const size_t fb = (size_t)(n0 / 16 + wave) * NKS * 512 + (size_t)lane * 8;
  auto ldW = [&](int s, u32x4& w0, u32x4& w1) {
    const size_t o0 = fb + (size_t)(2 * s) * 512;
    w0 = *(const u32x4*)(wf + o0);
    w1 = *(const u32x4*)(wf + o0 + 512);
  };

  auto body = [&](int s, int cur, u32x4& fW0, u32x4& fW1) {
    bf16x8 a0[4], a1[4];
#pragma unroll
    for (int j = 0; j < 4; ++j) {
      a0[j] = bc16(&As[cur][(j * 16 + ln) * LDK + lg * 8]);
      a1[j] = bc16(&As[cur][(j * 16 + ln) * LDK + 32 + lg * 8]);
    }
    if (s + 1 < NS64) {
      stageA(cur ^ 1);
      if (s + 2 < NS64) pfA((s + 2) * 64);
    }
    bf16x8 w0 = __builtin_bit_cast(bf16x8, fW0), w1 = __builtin_bit_cast(bf16x8, fW1);
#pragma unroll
    for (int j = 0; j < 4; ++j)
      acc[j] = __builtin_amdgcn_mfma_f32_16x16x32_bf16(a0[j], w0, acc[j], 0, 0, 0);
#pragma unroll
    for (int j = 0; j < 4; ++j)
      acc[j] = __builtin_amdgcn_mfma_f32_16x16x32_bf16(a1[j], w1, acc[j], 0, 0, 0);
    __syncthreads();
  };

  pfA(0);
  stageA(0);
  pfA(64);
  u32x4 wA0, wA1, wB0, wB1;
  ldW(0, wA0, wA1);
  ldW(1, wB0, wB1);
  __syncthreads();

  for (int s = 0; s < NS64; s += 2) {
    body(s, 0, wA0, wA1);
    if (s + 2 < NS64) ldW(s + 2, wA0, wA1);
    body(s + 1, 1, wB0, wB1);
    if (s + 3 < NS64) ldW(s + 3, wB0, wB1);
  }

  const int col = n0 + wave * 16 + ln;
  const float bv = bias[col];
#pragma unroll
  for (int j = 0; j < 4; ++j) {
    const int rowb = m0 + j * 16 + lg * 4;
#pragma unroll
    for (int r = 0; r < 4; ++r) out[(size_t)(rowb + r) * DIM + col] = acc[j][r] + bv;
  }
}

// ---------------- flash attention: K+V LDS dbuf, maxless exp2 softmax ----------------
// Grid 768 (64 q-tiles x 12 heads, XCD-swizzled), 4 waves = 2 q-groups x 2
// key-parities. Wave (g,p): q rows qt*64+g*32.., keys t*64+p*32.
// l_ cross-half exchange deferred to after the loop (sum is linear in the
// fixed lane^32 pairing).
__global__ __launch_bounds__(256, 3) void attn_kernel(const u16* __restrict__ Q,
                                                      const u16* __restrict__ K,
                                                      const u16* __restrict__ Vt,
                                                      u16* __restrict__ AO) {
  __shared__ alignas(16) u16 Ks[2][64 * LDT];  // [buf][key][d]
  __shared__ alignas(16) u16 Vs[2][64 * LDT];  // [buf][d][key]
  __shared__ float slx[4][32];

  const int tid = threadIdx.x, lane = tid & 63, wave = tid >> 6;
  const int l31 = lane & 31, hi = lane >> 5;
  const int g = wave >> 1, p = wave & 1;
  const int bid = blockIdx.x;
  const int swz = (bid & 7) * 96 + (bid >> 3);  // 768 = 8*96
  const int h = swz >> 6;
  const int q0 = (swz & 63) * 64;
  const int qw = q0 + g * 32;

  bf16x8 qf[4];
#pragma unroll
  for (int c = 0; c < 4; ++c)
    qf[c] = bc16(Q + (size_t)(qw + l31) * DIM + h * HD + c * 16 + hi * 8);

  float l_ = 0.f;  // half-sum; partner half added once after the loop
  f32x16 oacc[2] = {};

  const int srow = tid >> 2;
  const int scol = (tid & 3) * 16;
  const u16* Kh = K + (size_t)h * HD;
  const u16* Vh = Vt + (size_t)h * HD * SEQ;
  constexpr int NT = SEQ / 64;

  u32x4 kp0, kp1, vp0, vp1;
  auto pf = [&](int t) {
    const u32x4* s = (const u32x4*)(Kh + (size_t)(t * 64 + srow) * DIM + scol);
    kp0 = s[0]; kp1 = s[1];
    const u32x4* v = (const u32x4*)(Vh + (size_t)srow * SEQ + t * 64 + scol);
    vp0 = v[0]; vp1 = v[1];
  };
  auto stage = [&](int buf) {
    u16* kd = &Ks[buf][srow * LDT + scol];
    *(u32x4*)kd = kp0; *(u32x4*)(kd + 8) = kp1;
    u16* vd = &Vs[buf][srow * LDT + scol];
    *(u32x4*)vd = vp0; *(u32x4*)(vd + 8) = vp1;
  };

  pf(0);
  stage(0);
  pf(1);
  __syncthreads();

  auto round = [&](int t, int cur) {
    const int kr = (p * 32 + l31) * LDT + hi * 8;
    bf16x8 kf0 = bc16(&Ks[cur][kr]);
    bf16x8 kf1 = bc16(&Ks[cur][kr + 16]);
    bf16x8 kf2 = bc16(&Ks[cur][kr + 32]);
    bf16x8 kf3 = bc16(&Ks[cur][kr + 48]);
    const int vr0 = l31 * LDT + p * 32 + hi * 8;
    const int vr1 = (32 + l31) * LDT + p * 32 + hi * 8;
    bf16x8 vf00 = bc16(&Vs[cur][vr0]);
    bf16x8 vf01 = bc16(&Vs[cur][vr0 + 16]);
    bf16x8 vf10 = bc16(&Vs[cur][vr1]);
    bf16x8 vf11 = bc16(&Vs[cur][vr1 + 16]);

    if (t + 1 < NT) {
      stage(cur ^ 1);
      pf(t + 2 < NT ? t + 2 : t + 1);
    }

    f32x16 st = {};
    __builtin_amdgcn_s_setprio(1);
    st = __builtin_amdgcn_mfma_f32_32x32x16_bf16(kf0, qf[0], st, 0, 0, 0);
    st = __builtin_amdgcn_mfma_f32_32x32x16_bf16(kf1, qf[1], st, 0, 0, 0);
    st = __builtin_amdgcn_mfma_f32_32x32x16_bf16(kf2, qf[2], st, 0, 0, 0);
    st = __builtin_amdgcn_mfma_f32_32x32x16_bf16(kf3, qf[3], st, 0, 0, 0);
    __builtin_amdgcn_s_setprio(0);

#pragma unroll
    for (int r = 0; r < 16; ++r) st[r] = __builtin_amdgcn_exp2f(st[r]);

    {
      float s0 = (st[0] + st[4]) + (st[8] + st[12]);
      float s1 = (st[1] + st[5]) + (st[9] + st[13]);
      float s2 = (st[2] + st[6]) + (st[10] + st[14]);
      float s3 = (st[3] + st[7]) + (st[11] + st[15]);
      l_ += (s0 + s1) + (s2 + s3);  // partner half added after the loop
    }

    unsigned c0 = cvtpk_bf16(st[0], st[1]), c1 = cvtpk_bf16(st[2], st[3]);
    unsigned c2 = cvtpk_bf16(st[4], st[5]), c3 = cvtpk_bf16(st[6], st[7]);
    unsigned c4 = cvtpk_bf16(st[8], st[9]), c5 = cvtpk_bf16(st[10], st[11]);
    unsigned c6 = cvtpk_bf16(st[12], st[13]), c7 = cvtpk_bf16(st[14], st[15]);
    swap32(c0, c2); swap32(c1, c3); swap32(c4, c6); swap32(c5, c7);
    bf16x8 pa0 = __builtin_bit_cast(bf16x8, u32x4{c0, c1, c2, c3});
    bf16x8 pa1 = __builtin_bit_cast(bf16x8, u32x4{c4, c5, c6, c7});

    __builtin_amdgcn_s_setprio(1);
    oacc[0] = __builtin_amdgcn_mfma_f32_32x32x16_bf16(pa0, vf00, oacc[0], 0, 0, 0);
    oacc[0] = __builtin_amdgcn_mfma_f32_32x32x16_bf16(pa1, vf01, oacc[0], 0, 0, 0);
    oacc[1] = __builtin_amdgcn_mfma_f32_32x32x16_bf16(pa0, vf10, oacc[1], 0, 0, 0);
    oacc[1] = __builtin_amdgcn_mfma_f32_32x32x16_bf16(pa1, vf11, oacc[1], 0, 0, 0);
    __builtin_amdgcn_s_setprio(0);
    __syncthreads();
  };

  for (int t = 0; t < NT; t += 2) {
    round(t, 0);
    round(t + 1, 1);
  }

  // fold in the partner half once (fixed lane^32 pairing; sum is linear)
  l_ += partner32(l_, hi);

  if (hi == 0) slx[wave][l31] = l_;
  __syncthreads();

  const float L = slx[g * 2][l31] + slx[g * 2 + 1][l31];
  const float Linv = 1.f / L;
  float Lr[16];
#pragma unroll
  for (int r = 0; r < 16; ++r)
    Lr[r] = __shfl(Linv, (r & 3) + 8 * (r >> 2) + 4 * hi);

  float* Om = (float*)Ks;  // overlay: 64 x LDM f32 = 17408 B (Ks spans 18432)
  if (p == 1) {
#pragma unroll
    for (int nd = 0; nd < 2; ++nd)
#pragma unroll
      for (int r = 0; r < 16; ++r) {
        const int row = (r & 3) + 8 * (r >> 2) + 4 * hi;
        Om[(g * 32 + row) * LDM + nd * 32 + l31] = oacc[nd][r];
      }
  }
  __syncthreads();
  if (p == 0) {
#pragma unroll
    for (int nd = 0; nd < 2; ++nd)
#pragma unroll
      for (int r = 0; r < 16; ++r) {
        const int row = (r & 3) + 8 * (r >> 2) + 4 * hi;
        const float v =
            (oacc[nd][r] + Om[(g * 32 + row) * LDM + nd * 32 + l31]) * Lr[r];
        AO[(size_t)(qw + row) * DIM + h * HD + nd * 32 + l31] = f2bf(v);
      }
  }
}

extern "C" void kernel_launch(void* const* d_in, const int* in_sizes, int n_in,
                              void* d_out, int out_size, void* d_ws, size_t ws_size,
                              hipStream_t stream) {
  const float* x = (const float*)d_in[0];
  const float* wq = (const float*)d_in[1];
  const float* bq = (const float*)d_in[2];
  const float* wk = (const float*)d_in[3];
  const float* bk = (const float*)d_in[4];
  const float* wv = (const float*)d_in[5];
  const float* bv = (const float*)d_in[6];
  const float* ww = (const float*)d_in[7];
  const float* bw = (const float*)d_in[8];

  const size_t mat = (size_t)SEQ * DIM;
  const size_t nw = (size_t)DIM * DIM;  // 589,824
  if (ws_size < 4 * mat * sizeof(u16)) {
    fprintf(stderr, "kernel_launch: ws too small (%zu)\n", ws_size);
    return;
  }
  u16* Qb = (u16*)d_ws;
  u16* Kb = Qb + mat;
  u16* Vtb = Kb + mat;     // [768][4096]
  u16* AOb = Vtb + mat;    // also xb (sequentially dead)
  u16* xb = AOb;
  u16* wqf = (u16*)d_out;  // frag tiles in d_out scratch (consumed pre-out_gemm)
  u16* wkf = wqf + nw;
  u16* wvf = wkf + nw;
  u16* wwf = Kb;           // K dead after attn

  prep_all<<<dim3(2400), dim3(256), 0, stream>>>(x, wq, wk, wv, xb, wqf, wkf, wvf);
  qkv_gemm<<<dim3(768), dim3(256), 0, stream>>>(xb, wqf, wkf, wvf, bq, bk, bv, Qb, Kb, Vtb);
  attn_kernel<<<dim3(768), dim3(256), 0, stream>>>(Qb, Kb, Vtb, AOb);
  prep_wfrag<<<dim3(288), dim3(256), 0, stream>>>(ww, wwf);
  out_gemm<<<dim3(768), dim3(256), 0, stream>>>(AOb, wwf, bw, (float*)d_out);
}